// Round 1
// baseline (1317.690 us; speedup 1.0000x reference)
//
#include <hip/hip_runtime.h>
#include <math.h>

// Problem constants
#define NB 1024     // nodes
#define FB 32       // F_IN
#define TB 24       // T
#define GB 64       // F_OUT
#define BB 8        // batch
#define EB 16384    // edges
#define MB 32768    // N*F
#define DB 768      // F*T
#define BTB 192     // B*T

__device__ __forceinline__ float wsum(float v){
  #pragma unroll
  for (int o = 32; o; o >>= 1) v += __shfl_down(v, o);
  return v;
}
__device__ __forceinline__ float wmax(float v){
  #pragma unroll
  for (int o = 32; o; o >>= 1) v = fmaxf(v, __shfl_down(v, o));
  return v;
}
__device__ __forceinline__ float sigm(float v){ return 1.f / (1.f + expf(-v)); }

// ---------------- temporal attention ----------------
// score[b,t,u] += sum_m x[b,m,t]*x[b,m,u], m-chunked with atomics
__global__ __launch_bounds__(256) void k_score_t(const float* __restrict__ x,
                                                 float* __restrict__ score){
  const int chunk = blockIdx.x, t = blockIdx.y, b = blockIdx.z;
  const float* xb = x + (size_t)b * MB * TB;
  float acc[TB];
  #pragma unroll
  for (int u = 0; u < TB; ++u) acc[u] = 0.f;
  const int m0 = chunk * 4096 + threadIdx.x;
  for (int it = 0; it < 16; ++it){
    const float* xr = xb + (size_t)(m0 + it * 256) * TB;
    float in[TB];
    #pragma unroll
    for (int q = 0; q < 6; ++q){
      float4 v = *(const float4*)(xr + q * 4);
      in[q*4+0] = v.x; in[q*4+1] = v.y; in[q*4+2] = v.z; in[q*4+3] = v.w;
    }
    const float vt = xr[t];   // scalar load (t is block-uniform) -> no reg-array dyn index
    #pragma unroll
    for (int u = 0; u < TB; ++u) acc[u] = fmaf(vt, in[u], acc[u]);
  }
  __shared__ float red[TB];
  if (threadIdx.x < TB) red[threadIdx.x] = 0.f;
  __syncthreads();
  const int lane = threadIdx.x & 63;
  #pragma unroll
  for (int u = 0; u < TB; ++u){
    float v = wsum(acc[u]);
    if (lane == 0) atomicAdd(&red[u], v);
  }
  __syncthreads();
  if (threadIdx.x < TB)
    atomicAdd(&score[((size_t)b * TB + t) * TB + threadIdx.x], red[threadIdx.x]);
}

// E_att[b] = softmax_rows(Ve @ sigmoid(score[b]) + be)
__global__ __launch_bounds__(64) void k_eatt(const float* __restrict__ score,
                                             const float* __restrict__ Ve,
                                             const float* __restrict__ be,
                                             float* __restrict__ Eatt){
  const int b = blockIdx.x;
  __shared__ float sg[576], Ar[576], Vel[576], bel[576];
  for (int i = threadIdx.x; i < 576; i += 64){
    sg[i] = sigm(score[(size_t)b * 576 + i]);
    Vel[i] = Ve[i]; bel[i] = be[i];
  }
  __syncthreads();
  for (int i = threadIdx.x; i < 576; i += 64){
    int t = i / 24, v = i % 24;
    float s = 0.f;
    #pragma unroll
    for (int u = 0; u < 24; ++u) s = fmaf(Vel[t*24+u], sg[u*24+v], s);
    Ar[i] = s + bel[i];
  }
  __syncthreads();
  if (threadIdx.x < 24){
    const int t = threadIdx.x;
    float mx = -1e30f;
    #pragma unroll
    for (int v = 0; v < 24; ++v) mx = fmaxf(mx, Ar[t*24+v]);
    float e[24]; float sum = 0.f;
    #pragma unroll
    for (int v = 0; v < 24; ++v){ e[v] = expf(Ar[t*24+v] - mx); sum += e[v]; }
    const float inv = 1.f / sum;
    #pragma unroll
    for (int v = 0; v < 24; ++v) Eatt[(size_t)b * 576 + t*24 + v] = e[v] * inv;
  }
}

// xTA[b,m,v] = sum_u x[b,m,u] * E[b,u,v]
__global__ __launch_bounds__(256) void k_xta(const float* __restrict__ x,
                                             const float* __restrict__ Eatt,
                                             float* __restrict__ xTA){
  __shared__ float E[576];
  const int b = blockIdx.x >> 7;   // 128 blocks per batch
  for (int i = threadIdx.x; i < 576; i += 256) E[i] = Eatt[(size_t)b * 576 + i];
  __syncthreads();
  const size_t m = (size_t)blockIdx.x * 256 + threadIdx.x;
  const float* xr = x + m * TB;
  float in[TB], out[TB];
  #pragma unroll
  for (int q = 0; q < 6; ++q){
    float4 v = *(const float4*)(xr + q * 4);
    in[q*4+0] = v.x; in[q*4+1] = v.y; in[q*4+2] = v.z; in[q*4+3] = v.w;
  }
  #pragma unroll
  for (int v = 0; v < TB; ++v) out[v] = 0.f;
  #pragma unroll
  for (int u = 0; u < TB; ++u){
    const float xv = in[u];
    #pragma unroll
    for (int v = 0; v < TB; ++v) out[v] = fmaf(xv, E[u*24+v], out[v]);
  }
  float* op = xTA + m * TB;
  #pragma unroll
  for (int q = 0; q < 6; ++q){
    float4 v = make_float4(out[q*4+0], out[q*4+1], out[q*4+2], out[q*4+3]);
    *(float4*)(op + q * 4) = v;
  }
}

// ---------------- batched fp32 GEMM ----------------
// TRANSB=1: C[i,j] = sum_k A[i,k]*B[j,k];  TRANSB=0: C[i,j] = sum_k A[i,k]*B[k,j]
// SIG=1 applies sigmoid on store. 64x64 tile, 4x4 microtile, BK=16.
template<int TRANSB, int SIG>
__global__ __launch_bounds__(256) void k_gemm(const float* __restrict__ A,
                                              const float* __restrict__ B,
                                              float* __restrict__ C,
                                              int lda, int ldb, int ldc, int Kk,
                                              long sA, long sB, long sC){
  const int bz = blockIdx.z;
  A += (long)bz * sA; B += (long)bz * sB; C += (long)bz * sC;
  const int i0 = blockIdx.y * 64, j0 = blockIdx.x * 64;
  __shared__ float As[16][68];
  __shared__ float Bs[16][68];
  const int tid = threadIdx.x;
  const int tx = tid & 15, ty = tid >> 4;
  float acc[4][4];
  #pragma unroll
  for (int i = 0; i < 4; ++i)
    #pragma unroll
    for (int j = 0; j < 4; ++j) acc[i][j] = 0.f;
  const int lr = tid >> 2;        // 0..63
  const int lk = (tid & 3) * 4;   // 0,4,8,12
  const int br = tid >> 4;        // 0..15
  const int bc = (tid & 15) * 4;  // 0..60
  for (int k0 = 0; k0 < Kk; k0 += 16){
    float4 va = *(const float4*)&A[(size_t)(i0 + lr) * lda + k0 + lk];
    As[lk+0][lr] = va.x; As[lk+1][lr] = va.y; As[lk+2][lr] = va.z; As[lk+3][lr] = va.w;
    if (TRANSB){
      float4 vb = *(const float4*)&B[(size_t)(j0 + lr) * ldb + k0 + lk];
      Bs[lk+0][lr] = vb.x; Bs[lk+1][lr] = vb.y; Bs[lk+2][lr] = vb.z; Bs[lk+3][lr] = vb.w;
    } else {
      float4 vb = *(const float4*)&B[(size_t)(k0 + br) * ldb + j0 + bc];
      Bs[br][bc+0] = vb.x; Bs[br][bc+1] = vb.y; Bs[br][bc+2] = vb.z; Bs[br][bc+3] = vb.w;
    }
    __syncthreads();
    #pragma unroll
    for (int k = 0; k < 16; ++k){
      float4 av = *(const float4*)&As[k][ty * 4];
      float4 bv = *(const float4*)&Bs[k][tx * 4];
      float a4[4] = {av.x, av.y, av.z, av.w};
      float b4[4] = {bv.x, bv.y, bv.z, bv.w};
      #pragma unroll
      for (int i = 0; i < 4; ++i)
        #pragma unroll
        for (int j = 0; j < 4; ++j) acc[i][j] = fmaf(a4[i], b4[j], acc[i][j]);
    }
    __syncthreads();
  }
  #pragma unroll
  for (int i = 0; i < 4; ++i){
    float o0 = acc[i][0], o1 = acc[i][1], o2 = acc[i][2], o3 = acc[i][3];
    if (SIG){ o0 = sigm(o0); o1 = sigm(o1); o2 = sigm(o2); o3 = sigm(o3); }
    *(float4*)&C[(size_t)(i0 + ty*4 + i) * ldc + j0 + tx*4] = make_float4(o0, o1, o2, o3);
  }
}

// row softmax of (C2 + bs) over last dim (1024), in place
__global__ __launch_bounds__(256) void k_softmax_s(float* __restrict__ C2,
                                                   const float* __restrict__ bs){
  const int blk = blockIdx.x;
  const int n = blk & 1023;
  float* row = C2 + (size_t)blk * 1024;
  const float* bsr = bs + (size_t)n * 1024;
  const int tid = threadIdx.x;
  float4 v = *(const float4*)(row + tid * 4);
  float4 bb = *(const float4*)(bsr + tid * 4);
  v.x += bb.x; v.y += bb.y; v.z += bb.z; v.w += bb.w;
  float mx = fmaxf(fmaxf(v.x, v.y), fmaxf(v.z, v.w));
  mx = wmax(mx);
  __shared__ float s4[4];
  __shared__ float s4b[4];
  if ((tid & 63) == 0) s4[tid >> 6] = mx;
  __syncthreads();
  mx = fmaxf(fmaxf(s4[0], s4[1]), fmaxf(s4[2], s4[3]));
  float e0 = expf(v.x - mx), e1 = expf(v.y - mx), e2 = expf(v.z - mx), e3 = expf(v.w - mx);
  float sum = wsum(e0 + e1 + e2 + e3);
  if ((tid & 63) == 0) s4b[tid >> 6] = sum;
  __syncthreads();
  sum = s4b[0] + s4b[1] + s4b[2] + s4b[3];
  const float inv = 1.f / sum;
  *(float4*)(row + tid * 4) = make_float4(e0*inv, e1*inv, e2*inv, e3*inv);
}

// T0[bt,n,f] = xSA[b, n, f, t]   (xSA stored as (B,N,768) with d=f*24+t)
__global__ __launch_bounds__(256) void k_t0(const float* __restrict__ xSA,
                                            float* __restrict__ T0){
  const int b = blockIdx.y; const int n0 = blockIdx.x * 8;
  __shared__ float lds[8 * 768];
  const float* src = xSA + ((size_t)b * NB + n0) * DB;
  for (int i = threadIdx.x; i < 6144; i += 256) lds[i] = src[i];
  __syncthreads();
  for (int i = threadIdx.x; i < 6144; i += 256){
    int t = i >> 8; int rr = i & 255; int ln = rr >> 5; int f = rr & 31;
    T0[((size_t)(b * TB + t) * NB + n0 + ln) * FB + f] = lds[ln * DB + f * TB + t];
  }
}

// ---------------- ChebConv graph machinery ----------------
__global__ __launch_bounds__(256) void k_edge_deg(const int* __restrict__ ei,
                                                  const float* __restrict__ ew,
                                                  float* __restrict__ deg,
                                                  int* __restrict__ cnt){
  int e = blockIdx.x * 256 + threadIdx.x;
  if (e >= EB) return;
  int r = ei[e], c = ei[EB + e];
  float w = (r == c) ? 0.f : ew[e];
  atomicAdd(&deg[r], w);
  atomicAdd(&cnt[c], 1);
}

__global__ void k_scan(const int* __restrict__ cnt, int* __restrict__ ptr,
                       int* __restrict__ fill){
  if (threadIdx.x == 0 && blockIdx.x == 0){
    int s = 0;
    for (int i = 0; i < NB; ++i){ ptr[i] = s; fill[i] = s; s += cnt[i]; }
    ptr[NB] = s;
  }
}

__global__ __launch_bounds__(256) void k_edge_fill(const int* __restrict__ ei,
                                                   const float* __restrict__ ew,
                                                   const float* __restrict__ deg,
                                                   int* __restrict__ fill,
                                                   int* __restrict__ cidx,
                                                   float* __restrict__ normv){
  int e = blockIdx.x * 256 + threadIdx.x;
  if (e >= EB) return;
  int r = ei[e], c = ei[EB + e];
  float w = (r == c) ? 0.f : ew[e];
  float dr = deg[r], dc = deg[c];
  float ir = dr > 0.f ? rsqrtf(dr) : 0.f;
  float ic = dc > 0.f ? rsqrtf(dc) : 0.f;
  normv[e] = -ir * w * ic;
  int pos = atomicAdd(&fill[c], 1);
  cidx[pos] = e;
}

// out[bt,c,f] = scale * sum_{e in col c} norm[e]*z[bt,row[e],f]  (- sub[bt,c,f])
__global__ __launch_bounds__(256) void k_prop(const float* __restrict__ z,
                                              const float* __restrict__ normv,
                                              const int* __restrict__ cidx,
                                              const int* __restrict__ ei,
                                              const int* __restrict__ ptr,
                                              const float* __restrict__ sub,
                                              float scale,
                                              float* __restrict__ outz){
  const int bt = blockIdx.y;
  const int c = blockIdx.x * 8 + (threadIdx.x >> 5);
  const int f = threadIdx.x & 31;
  const float* zb = z + (size_t)bt * MB;
  float acc = 0.f;
  const int j1 = ptr[c + 1];
  for (int j = ptr[c]; j < j1; ++j){
    int e = cidx[j];
    int r = ei[e];
    acc = fmaf(normv[e], zb[r * FB + f], acc);
  }
  size_t oi = (size_t)bt * MB + (size_t)c * FB + f;
  float v = scale * acc;
  if (sub) v -= sub[oi];
  outz[oi] = v;
}

// ---------------- fused Cheb-matmul + residual + relu ----------------
__global__ __launch_bounds__(256) void k_final(const float* __restrict__ T0,
                                               const float* __restrict__ T1,
                                               const float* __restrict__ T2,
                                               const float* __restrict__ x,
                                               const float* __restrict__ chebW,
                                               const float* __restrict__ chebB,
                                               const float* __restrict__ resW,
                                               const float* __restrict__ resB,
                                               float* __restrict__ out){
  const int n = blockIdx.x; const int b = blockIdx.y;
  __shared__ float tr0[TB][33], tr1[TB][33], tr2[TB][33];
  __shared__ float xls[DB];
  __shared__ float wl[3 * 2048];
  __shared__ float rl[2048];
  __shared__ float cb[GB], rb[GB];
  const int tid = threadIdx.x;
  for (int i = tid; i < 6144; i += 256) wl[i] = chebW[i];
  for (int i = tid; i < 2048; i += 256) rl[i] = resW[i];
  if (tid < GB){ cb[tid] = chebB[tid]; rb[tid] = resB[tid]; }
  for (int i = tid; i < DB; i += 256){
    int t = i >> 5, f = i & 31;
    size_t gi = ((size_t)(b * TB + t) * NB + n) * FB + f;
    tr0[t][f] = T0[gi]; tr1[t][f] = T1[gi]; tr2[t][f] = T2[gi];
  }
  {
    const size_t xb = (size_t)(b * NB + n) * DB;
    for (int i = tid; i < DB; i += 256) xls[i] = x[xb + i];
  }
  __syncthreads();
  const size_t base = (size_t)(b * NB + n) * GB * TB;
  for (int o = tid; o < GB * TB; o += 256){
    const int g = o / 24, t = o % 24;
    float s = cb[g] + rb[g];
    #pragma unroll
    for (int f = 0; f < FB; ++f){
      s = fmaf(tr0[t][f], wl[f * 64 + g], s);
      s = fmaf(tr1[t][f], wl[2048 + f * 64 + g], s);
      s = fmaf(tr2[t][f], wl[4096 + f * 64 + g], s);
      s = fmaf(xls[f * 24 + t], rl[g * 32 + f], s);
    }
    out[base + o] = fmaxf(s, 0.f);
  }
}

extern "C" void kernel_launch(void* const* d_in, const int* in_sizes, int n_in,
                              void* d_out, int out_size, void* d_ws, size_t ws_size,
                              hipStream_t stream){
  const float* x  = (const float*)d_in[0];
  const int*   ei = (const int*)d_in[1];
  const float* ew = (const float*)d_in[2];
  const float* Ve = (const float*)d_in[3];
  const float* be = (const float*)d_in[4];
  const float* Vs = (const float*)d_in[5];
  const float* bs = (const float*)d_in[6];
  const float* cW = (const float*)d_in[7];
  const float* cB = (const float*)d_in[8];
  const float* rW = (const float*)d_in[9];
  const float* rB = (const float*)d_in[10];
  float* out = (float*)d_out;

  float* W = (float*)d_ws;
  float* xTA  = W;                         // 6291456 floats; later reused as T0
  float* sig  = W + 6291456;               // 8388608; later xSA, later T2
  float* C2   = W + 6291456 + 8388608;     // 8388608; later T1
  float* score = C2 + 8388608;             // 4608
  float* Eatt  = score + 4608;             // 4608
  float* normv = Eatt + 4608;              // 16384
  float* deg   = normv + 16384;            // 1024
  int* cnt  = (int*)(deg + 1024);          // 1024
  int* ptr  = cnt + 1024;                  // 1025 (padded to 1028)
  int* fill = ptr + 1028;                  // 1024
  int* cidx = fill + 1024;                 // 16384

  hipMemsetAsync(score, 0, 4608 * sizeof(float), stream);
  hipMemsetAsync(deg, 0, 1024 * sizeof(float) + 1024 * sizeof(int), stream); // deg + cnt

  // temporal attention
  k_score_t<<<dim3(8, 24, 8), 256, 0, stream>>>(x, score);
  k_eatt<<<dim3(8), 64, 0, stream>>>(score, Ve, be, Eatt);
  k_xta<<<dim3(1024), 256, 0, stream>>>(x, Eatt, xTA);

  // spatial attention (sig(score_s) is symmetric -> GEMM2 is also A*B^T)
  k_gemm<1,1><<<dim3(16,16,8), 256, 0, stream>>>(xTA, xTA, sig, DB, DB, NB, DB,
                                                 (long)MB*TB, (long)MB*TB, (long)NB*NB);
  k_gemm<1,0><<<dim3(16,16,8), 256, 0, stream>>>(Vs, sig, C2, NB, NB, NB, NB,
                                                 0L, (long)NB*NB, (long)NB*NB);
  k_softmax_s<<<dim3(8192), 256, 0, stream>>>(C2, bs);
  k_gemm<0,0><<<dim3(12,16,8), 256, 0, stream>>>(C2, xTA, sig /*xSA*/, NB, DB, DB, NB,
                                                 (long)NB*NB, (long)MB*TB, (long)MB*TB);

  // ChebConv: layout transform + CSR build + 2 props
  k_t0<<<dim3(128, 8), 256, 0, stream>>>(sig /*xSA*/, xTA /*T0*/);
  k_edge_deg<<<dim3(64), 256, 0, stream>>>(ei, ew, deg, cnt);
  k_scan<<<dim3(1), 64, 0, stream>>>(cnt, ptr, fill);
  k_edge_fill<<<dim3(64), 256, 0, stream>>>(ei, ew, deg, fill, cidx, normv);
  k_prop<<<dim3(128, 192), 256, 0, stream>>>(xTA /*T0*/, normv, cidx, ei, ptr,
                                             nullptr, 1.f, C2 /*T1*/);
  k_prop<<<dim3(128, 192), 256, 0, stream>>>(C2 /*T1*/, normv, cidx, ei, ptr,
                                             xTA /*T0*/, 2.f, sig /*T2*/);

  // fused Cheb matmuls + residual + relu
  k_final<<<dim3(1024, 8), 256, 0, stream>>>(xTA, C2, sig, x, cW, cB, rW, rB, out);
}

// Round 2
// 600.677 us; speedup vs baseline: 2.1937x; 2.1937x over previous
//
#include <hip/hip_runtime.h>
#include <math.h>

// Problem constants
#define NB 1024     // nodes
#define FB 32       // F_IN
#define TB 24       // T
#define GB 64       // F_OUT
#define BB 8        // batch
#define EB 16384    // edges
#define MB 32768    // N*F
#define DB 768      // F*T
#define BTB 192     // B*T

typedef __attribute__((ext_vector_type(8))) short sh8;     // 8 bf16 (4 VGPRs)
typedef __attribute__((ext_vector_type(4))) float f32x4;   // MFMA accumulator

__device__ __forceinline__ float wsum(float v){
  #pragma unroll
  for (int o = 32; o; o >>= 1) v += __shfl_down(v, o);
  return v;
}
__device__ __forceinline__ float wmax(float v){
  #pragma unroll
  for (int o = 32; o; o >>= 1) v = fmaxf(v, __shfl_down(v, o));
  return v;
}
__device__ __forceinline__ float sigm(float v){ return 1.f / (1.f + expf(-v)); }
__device__ __forceinline__ float b2f(unsigned short u){ unsigned int t = ((unsigned int)u) << 16; return __uint_as_float(t); }
__device__ __forceinline__ unsigned short f2b(float f){
  unsigned int u = __float_as_uint(f);
  u += 0x7fffu + ((u >> 16) & 1u);
  return (unsigned short)(u >> 16);
}
__device__ __forceinline__ void gload16(const void* g, void* l){
  typedef const __attribute__((address_space(1))) unsigned int* gp_t;
  typedef __attribute__((address_space(3))) unsigned int* lp_t;
  __builtin_amdgcn_global_load_lds((gp_t)g, (lp_t)l, 16, 0, 0);
}

// ---------------- temporal attention ----------------
// one-pass Gram: score[b,t,u] += sum over 512-row chunk of x[b,m,t]*x[b,m,u]
__global__ __launch_bounds__(256) void k_score(const float* __restrict__ x,
                                               float* __restrict__ score){
  const int b = blockIdx.y, ch = blockIdx.x;   // 64 chunks of 512 rows
  __shared__ float xs[512 * 24];
  const float* src = x + (size_t)b * (MB * TB) + (size_t)ch * 512 * 24;
  #pragma unroll
  for (int p = 0; p < 12; ++p){
    int i = p * 256 + threadIdx.x;
    ((float4*)xs)[i] = ((const float4*)src)[i];
  }
  __syncthreads();
  if (threadIdx.x < 192){
    const int t = threadIdx.x >> 3, u0 = (threadIdx.x & 7) * 3;
    float a0 = 0.f, a1 = 0.f, a2 = 0.f;
    for (int m = 0; m < 512; ++m){
      const float xt = xs[m * 24 + t];
      a0 = fmaf(xt, xs[m * 24 + u0 + 0], a0);
      a1 = fmaf(xt, xs[m * 24 + u0 + 1], a1);
      a2 = fmaf(xt, xs[m * 24 + u0 + 2], a2);
    }
    float* sb = score + (size_t)b * 576 + t * 24 + u0;
    atomicAdd(sb + 0, a0); atomicAdd(sb + 1, a1); atomicAdd(sb + 2, a2);
  }
}

// E_att[b] = softmax_rows(Ve @ sigmoid(score[b]) + be)
__global__ __launch_bounds__(64) void k_eatt(const float* __restrict__ score,
                                             const float* __restrict__ Ve,
                                             const float* __restrict__ be,
                                             float* __restrict__ Eatt){
  const int b = blockIdx.x;
  __shared__ float sg[576], Ar[576], Vel[576], bel[576];
  for (int i = threadIdx.x; i < 576; i += 64){
    sg[i] = sigm(score[(size_t)b * 576 + i]);
    Vel[i] = Ve[i]; bel[i] = be[i];
  }
  __syncthreads();
  for (int i = threadIdx.x; i < 576; i += 64){
    int t = i / 24, v = i % 24;
    float s = 0.f;
    #pragma unroll
    for (int u = 0; u < 24; ++u) s = fmaf(Vel[t*24+u], sg[u*24+v], s);
    Ar[i] = s + bel[i];
  }
  __syncthreads();
  if (threadIdx.x < 24){
    const int t = threadIdx.x;
    float mx = -1e30f;
    #pragma unroll
    for (int v = 0; v < 24; ++v) mx = fmaxf(mx, Ar[t*24+v]);
    float e[24]; float sum = 0.f;
    #pragma unroll
    for (int v = 0; v < 24; ++v){ e[v] = expf(Ar[t*24+v] - mx); sum += e[v]; }
    const float inv = 1.f / sum;
    #pragma unroll
    for (int v = 0; v < 24; ++v) Eatt[(size_t)b * 576 + t*24 + v] = e[v] * inv;
  }
}

// xTA_h[b,m,v] = bf16( sum_u x[b,m,u] * E[b,u,v] )
__global__ __launch_bounds__(256) void k_xta(const float* __restrict__ x,
                                             const float* __restrict__ Eatt,
                                             unsigned short* __restrict__ xh){
  __shared__ float E[576];
  const int b = blockIdx.x >> 7;   // 128 blocks per batch
  for (int i = threadIdx.x; i < 576; i += 256) E[i] = Eatt[(size_t)b * 576 + i];
  __syncthreads();
  const size_t m = (size_t)blockIdx.x * 256 + threadIdx.x;
  const float* xr = x + m * TB;
  float in[TB], o[TB];
  #pragma unroll
  for (int q = 0; q < 6; ++q){
    float4 v = *(const float4*)(xr + q * 4);
    in[q*4+0] = v.x; in[q*4+1] = v.y; in[q*4+2] = v.z; in[q*4+3] = v.w;
  }
  #pragma unroll
  for (int v = 0; v < TB; ++v) o[v] = 0.f;
  #pragma unroll
  for (int u = 0; u < TB; ++u){
    const float xv = in[u];
    #pragma unroll
    for (int v = 0; v < TB; ++v) o[v] = fmaf(xv, E[u*24+v], o[v]);
  }
  unsigned int pk[12];
  #pragma unroll
  for (int q = 0; q < 12; ++q)
    pk[q] = (unsigned int)f2b(o[2*q]) | ((unsigned int)f2b(o[2*q+1]) << 16);
  uint4* op = (uint4*)(xh + m * TB);
  op[0] = make_uint4(pk[0], pk[1], pk[2], pk[3]);
  op[1] = make_uint4(pk[4], pk[5], pk[6], pk[7]);
  op[2] = make_uint4(pk[8], pk[9], pk[10], pk[11]);
}

// transpose per batch: (1024 x 768) -> (768 x 1024), bf16
__global__ __launch_bounds__(256) void k_tr(const unsigned short* __restrict__ in,
                                            unsigned short* __restrict__ out){
  const int dt = blockIdx.x, nt = blockIdx.y, b = blockIdx.z;
  __shared__ unsigned short ts[64 * 66];
  const unsigned short* ib = in + (size_t)b * (NB * DB) + (size_t)(nt * 64) * DB + dt * 64;
  #pragma unroll
  for (int p = 0; p < 8; ++p){
    int fl = p * 256 + threadIdx.x;        // 2048 uint loads
    int rr = fl >> 5, cc = (fl & 31) * 2;
    unsigned int v = *(const unsigned int*)(ib + (size_t)rr * DB + cc);
    ts[rr * 66 + cc] = (unsigned short)v;
    ts[rr * 66 + cc + 1] = (unsigned short)(v >> 16);
  }
  __syncthreads();
  unsigned short* ob = out + (size_t)b * (NB * DB) + (size_t)(dt * 64) * NB + nt * 64;
  #pragma unroll
  for (int p = 0; p < 16; ++p){
    int fl = p * 256 + threadIdx.x;        // 4096 elems
    int dd = fl >> 6, nn = fl & 63;
    ob[(size_t)dd * NB + nn] = ts[nn * 66 + dd];
  }
}

// ---------------- bf16 MFMA GEMM: C[i,j] = sum_k A[i,k]*B[j,k] ----------------
// A:(MxK) bf16 row-major, B:(NxK) bf16 row-major. 128x128 tile, BK=64, 4 waves 2x2.
// EPI: 1 = sigmoid -> bf16 store, 2 = plain -> bf16 store
template<int EPI>
__global__ __launch_bounds__(256) void k_mgemm(const unsigned short* __restrict__ A,
                                               const unsigned short* __restrict__ B,
                                               unsigned short* __restrict__ C,
                                               int lda, int ldb, int ldc, int Kk,
                                               long sA, long sB, long sC){
  __shared__ unsigned short As[8192];
  __shared__ unsigned short Bs[8192];
  const int bz = blockIdx.z;
  A += (size_t)bz * sA; B += (size_t)bz * sB; C += (size_t)bz * sC;
  const int i0 = blockIdx.y * 128, j0 = blockIdx.x * 128;
  const int tid = threadIdx.x, wave = tid >> 6, lane = tid & 63;
  const int fr = lane & 15, fg = (lane >> 4) * 8, rowb = (lane >> 4) * 4;
  const int wr = (wave >> 1) * 64, wc = (wave & 1) * 64;
  const int srow = tid >> 3, sko = (tid & 7) * 8;
  f32x4 acc[4][4];
  #pragma unroll
  for (int m = 0; m < 4; ++m)
    #pragma unroll
    for (int n = 0; n < 4; ++n) acc[m][n] = 0.f;

  for (int k0 = 0; k0 < Kk; k0 += 64){
    #pragma unroll
    for (int it = 0; it < 4; ++it){
      const int r = it * 32 + srow;
      gload16(A + (size_t)(i0 + r) * lda + k0 + sko, &As[(it*4 + wave) * 512]);
      gload16(B + (size_t)(j0 + r) * ldb + k0 + sko, &Bs[(it*4 + wave) * 512]);
    }
    __syncthreads();
    #pragma unroll
    for (int kk = 0; kk < 2; ++kk){
      sh8 af[4], bfr[4];
      #pragma unroll
      for (int m = 0; m < 4; ++m)
        af[m] = *(const sh8*)&As[(wr + m*16 + fr) * 64 + kk*32 + fg];
      #pragma unroll
      for (int n = 0; n < 4; ++n)
        bfr[n] = *(const sh8*)&Bs[(wc + n*16 + fr) * 64 + kk*32 + fg];
      #pragma unroll
      for (int m = 0; m < 4; ++m)
        #pragma unroll
        for (int n = 0; n < 4; ++n)
          acc[m][n] = __builtin_amdgcn_mfma_f32_16x16x32_bf16(af[m], bfr[n], acc[m][n], 0, 0, 0);
    }
    __syncthreads();
  }
  #pragma unroll
  for (int m = 0; m < 4; ++m){
    const int row = i0 + wr + m*16 + rowb;
    #pragma unroll
    for (int n = 0; n < 4; ++n){
      const int colg = j0 + wc + n*16 + fr;
      #pragma unroll
      for (int r = 0; r < 4; ++r){
        float v = acc[m][n][r];
        if (EPI == 1) v = sigm(v);
        C[(size_t)(row + r) * ldc + colg] = f2b(v);
      }
    }
  }
}

// row softmax of (b2f(C2h) + bs) over last dim (1024) -> bf16 Sh
__global__ __launch_bounds__(256) void k_softmax_s(const unsigned short* __restrict__ C2h,
                                                   const float* __restrict__ bs,
                                                   unsigned short* __restrict__ Sh){
  const int blk = blockIdx.x;
  const int n = blk & 1023;
  const unsigned short* row = C2h + (size_t)blk * 1024;
  const float* bsr = bs + (size_t)n * 1024;
  const int tid = threadIdx.x;
  uint2 rv = ((const uint2*)row)[tid];
  float4 bb = ((const float4*)bsr)[tid];
  float v0 = b2f((unsigned short)rv.x)         + bb.x;
  float v1 = b2f((unsigned short)(rv.x >> 16)) + bb.y;
  float v2 = b2f((unsigned short)rv.y)         + bb.z;
  float v3 = b2f((unsigned short)(rv.y >> 16)) + bb.w;
  float mx = fmaxf(fmaxf(v0, v1), fmaxf(v2, v3));
  mx = wmax(mx);
  __shared__ float s4[4];
  __shared__ float s4b[4];
  if ((tid & 63) == 0) s4[tid >> 6] = mx;
  __syncthreads();
  mx = fmaxf(fmaxf(s4[0], s4[1]), fmaxf(s4[2], s4[3]));
  float e0 = expf(v0 - mx), e1 = expf(v1 - mx), e2 = expf(v2 - mx), e3 = expf(v3 - mx);
  float sum = wsum(e0 + e1 + e2 + e3);
  if ((tid & 63) == 0) s4b[tid >> 6] = sum;
  __syncthreads();
  sum = s4b[0] + s4b[1] + s4b[2] + s4b[3];
  const float inv = 1.f / sum;
  uint2 ov;
  ov.x = (unsigned int)f2b(e0 * inv) | ((unsigned int)f2b(e1 * inv) << 16);
  ov.y = (unsigned int)f2b(e2 * inv) | ((unsigned int)f2b(e3 * inv) << 16);
  ((uint2*)(Sh + (size_t)blk * 1024))[tid] = ov;
}

// T0h[bt,n,f] = xSA_h[b, n, f*24+t]
__global__ __launch_bounds__(256) void k_t0h(const unsigned short* __restrict__ xSAh,
                                             unsigned short* __restrict__ T0h){
  const int n0 = blockIdx.x * 8, b = blockIdx.y;
  __shared__ unsigned short s[6144];
  const unsigned int* src = (const unsigned int*)(xSAh + ((size_t)b * NB + n0) * DB);
  #pragma unroll
  for (int p = 0; p < 12; ++p) ((unsigned int*)s)[p*256 + threadIdx.x] = src[p*256 + threadIdx.x];
  __syncthreads();
  #pragma unroll
  for (int p = 0; p < 24; ++p){
    int flat = p * 256 + threadIdx.x;
    int t = flat >> 8, rr = flat & 255, nn = rr >> 5, f = rr & 31;
    T0h[((size_t)(b * TB + t) * NB + n0 + nn) * FB + f] = s[nn * DB + f * TB + t];
  }
}

// ---------------- ChebConv graph machinery ----------------
__global__ __launch_bounds__(256) void k_edge_deg(const int* __restrict__ ei,
                                                  const float* __restrict__ ew,
                                                  float* __restrict__ deg,
                                                  int* __restrict__ cnt){
  int e = blockIdx.x * 256 + threadIdx.x;
  if (e >= EB) return;
  int r = ei[e], c = ei[EB + e];
  float w = (r == c) ? 0.f : ew[e];
  atomicAdd(&deg[r], w);
  atomicAdd(&cnt[c], 1);
}

__global__ __launch_bounds__(1024) void k_scan(const int* __restrict__ cnt,
                                               int* __restrict__ ptr,
                                               int* __restrict__ fill){
  __shared__ int sd[1024];
  const int i = threadIdx.x;
  int c = cnt[i];
  sd[i] = c;
  __syncthreads();
  int v = c;
  for (int s = 1; s < 1024; s <<= 1){
    int t = (i >= s) ? sd[i - s] : 0;
    __syncthreads();
    v += t; sd[i] = v;
    __syncthreads();
  }
  ptr[i + 1] = v;
  fill[i] = v - c;
  if (i == 0) ptr[0] = 0;
}

__global__ __launch_bounds__(256) void k_edge_fill(const int* __restrict__ ei,
                                                   const float* __restrict__ ew,
                                                   const float* __restrict__ deg,
                                                   int* __restrict__ fill,
                                                   int* __restrict__ cidx,
                                                   float* __restrict__ normv){
  int e = blockIdx.x * 256 + threadIdx.x;
  if (e >= EB) return;
  int r = ei[e], c = ei[EB + e];
  float w = (r == c) ? 0.f : ew[e];
  float dr = deg[r], dc = deg[c];
  float ir = dr > 0.f ? rsqrtf(dr) : 0.f;
  float ic = dc > 0.f ? rsqrtf(dc) : 0.f;
  normv[e] = -ir * w * ic;
  int pos = atomicAdd(&fill[c], 1);
  cidx[pos] = e;
}

// outz[bt,c,f] = bf16( scale * sum_{e: col==c} norm[e]*z[bt,row[e],f]  - sub[bt,c,f] )
__global__ __launch_bounds__(256) void k_prop(const unsigned short* __restrict__ z,
                                              const float* __restrict__ normv,
                                              const int* __restrict__ cidx,
                                              const int* __restrict__ ei,
                                              const int* __restrict__ ptr,
                                              const unsigned short* __restrict__ sub,
                                              float scale,
                                              unsigned short* __restrict__ outz){
  const int bt = blockIdx.y;
  const int c = blockIdx.x * 8 + (threadIdx.x >> 5);
  const int f = threadIdx.x & 31;
  const unsigned short* zb = z + (size_t)bt * MB;
  float acc = 0.f;
  const int j1 = ptr[c + 1];
  for (int j = ptr[c]; j < j1; ++j){
    int e = cidx[j];
    int r = ei[e];
    acc = fmaf(normv[e], b2f(zb[r * FB + f]), acc);
  }
  size_t oi = (size_t)bt * MB + (size_t)c * FB + f;
  float v = scale * acc;
  if (sub) v -= b2f(sub[oi]);
  outz[oi] = f2b(v);
}

// ---------------- fused final GEMM: Ct[bt,n,g] = relu(A[n,:]@W[:,g] + bias) ----------------
// A row = [T0h | T1h | T2h | xTh] (K=128), tile 128 nodes x 64 g, single K-tile.
__global__ __launch_bounds__(256) void k_fgemm(const unsigned short* __restrict__ T0h,
                                               const unsigned short* __restrict__ T1h,
                                               const unsigned short* __restrict__ T2h,
                                               const unsigned short* __restrict__ xTh,
                                               const unsigned short* __restrict__ Wh,
                                               const float* __restrict__ bsum,
                                               unsigned short* __restrict__ Ct){
  __shared__ unsigned short As[16384];
  __shared__ unsigned short Ws[8192];
  const int n0 = blockIdx.x * 128, bt = blockIdx.y;
  const int tid = threadIdx.x, wave = tid >> 6, lane = tid & 63;
  const int fr = lane & 15, fg = (lane >> 4) * 8, rowb = (lane >> 4) * 4;
  const int wr = (wave >> 1) * 64, wc = (wave & 1) * 32;
  #pragma unroll
  for (int it = 0; it < 8; ++it){
    int flat = (it * 256 + tid) * 8;
    int row = flat >> 7, ko = flat & 127;
    int ss = ko >> 5, off = ko & 31;
    const unsigned short* bp = (ss == 0) ? T0h : (ss == 1) ? T1h : (ss == 2) ? T2h : xTh;
    gload16(bp + ((size_t)bt * NB + n0 + row) * FB + off, &As[(it*4 + wave) * 512]);
  }
  #pragma unroll
  for (int it = 0; it < 4; ++it)
    gload16(Wh + (size_t)(it * 256 + tid) * 8, &Ws[(it*4 + wave) * 512]);
  __syncthreads();
  f32x4 acc[4][2];
  #pragma unroll
  for (int m = 0; m < 4; ++m){ acc[m][0] = 0.f; acc[m][1] = 0.f; }
  #pragma unroll
  for (int kk = 0; kk < 4; ++kk){
    sh8 af[4], bf2[2];
    #pragma unroll
    for (int m = 0; m < 4; ++m)
      af[m] = *(const sh8*)&As[(wr + m*16 + fr) * 128 + kk*32 + fg];
    #pragma unroll
    for (int n = 0; n < 2; ++n)
      bf2[n] = *(const sh8*)&Ws[(wc + n*16 + fr) * 128 + kk*32 + fg];
    #pragma unroll
    for (int m = 0; m < 4; ++m)
      #pragma unroll
      for (int n = 0; n < 2; ++n)
        acc[m][n] = __builtin_amdgcn_mfma_f32_16x16x32_bf16(af[m], bf2[n], acc[m][n], 0, 0, 0);
  }
  #pragma unroll
  for (int n = 0; n < 2; ++n){
    const int g = wc + n*16 + fr;
    const float bv = bsum[g];
    #pragma unroll
    for (int m = 0; m < 4; ++m){
      const int node = n0 + wr + m*16 + rowb;
      #pragma unroll
      for (int r = 0; r < 4; ++r){
        float v = fmaxf(acc[m][n][r] + bv, 0.f);
        Ct[((size_t)bt * NB + node + r) * GB + g] = f2b(v);
      }
    }
  }
}

// out[b,n,g,t] = f32(Ct[(b*24+t), n, g])
__global__ __launch_bounds__(256) void k_outt(const unsigned short* __restrict__ Ct,
                                              float* __restrict__ out){
  const int n0 = blockIdx.x * 8, b = blockIdx.y;
  __shared__ unsigned short ls[24 * 520];
  for (int t = 0; t < 24; ++t){
    const unsigned int* src = (const unsigned int*)(Ct + ((size_t)(b * TB + t) * NB + n0) * GB);
    ((unsigned int*)&ls[t * 520])[threadIdx.x] = src[threadIdx.x];
  }
  __syncthreads();
  #pragma unroll
  for (int pp = 0; pp < 2; ++pp){
    int p = pp * 256 + threadIdx.x;
    int nn = p >> 6, g = p & 63;
    float o[24];
    #pragma unroll
    for (int t = 0; t < 24; ++t) o[t] = b2f(ls[t * 520 + nn * 64 + g]);
    float4* op = (float4*)(out + ((size_t)(b * NB + n0 + nn) * GB + g) * TB);
    #pragma unroll
    for (int q = 0; q < 6; ++q) op[q] = make_float4(o[q*4], o[q*4+1], o[q*4+2], o[q*4+3]);
  }
}

// ---------------- small converters ----------------
__global__ __launch_bounds__(256) void k_vsh(const float* __restrict__ Vs,
                                             unsigned short* __restrict__ Vsh){
  int i = (blockIdx.x * 256 + threadIdx.x) * 4;
  float4 v = *(const float4*)(Vs + i);
  unsigned short* o = Vsh + i;
  o[0] = f2b(v.x); o[1] = f2b(v.y); o[2] = f2b(v.z); o[3] = f2b(v.w);
}

// W_h[g][k]: k 0:32 cW[0], 32:64 cW[1], 64:96 cW[2], 96:128 resW; bsum = cB+rB
__global__ __launch_bounds__(256) void k_wcat(const float* __restrict__ cW,
                                              const float* __restrict__ cB,
                                              const float* __restrict__ rW,
                                              const float* __restrict__ rB,
                                              unsigned short* __restrict__ Wh,
                                              float* __restrict__ bsum){
  for (int i = threadIdx.x; i < 8192; i += 256){
    int g = i >> 7, k = i & 127;
    int s = k >> 5, f = k & 31;
    float v = (s < 3) ? cW[(s * 32 + f) * 64 + g] : rW[g * 32 + f];
    Wh[i] = f2b(v);
  }
  if (threadIdx.x < 64) bsum[threadIdx.x] = cB[threadIdx.x] + rB[threadIdx.x];
}

// xT_h[bt,n,f] = bf16(x[b,n,f,t])
__global__ __launch_bounds__(256) void k_xth(const float* __restrict__ x,
                                             unsigned short* __restrict__ xTh){
  const int n0 = blockIdx.x * 8, b = blockIdx.y;
  __shared__ float xl[8 * 32 * 25];
  const float* src = x + ((size_t)b * NB + n0) * DB;
  #pragma unroll
  for (int p = 0; p < 24; ++p){
    int i = p * 256 + threadIdx.x;       // 6144 floats
    int n = i / 768, rem = i % 768, f = rem / 24, t = rem % 24;
    xl[(n * 32 + f) * 25 + t] = src[i];
  }
  __syncthreads();
  #pragma unroll
  for (int p = 0; p < 24; ++p){
    int flat = p * 256 + threadIdx.x;
    int t = flat >> 8, rr = flat & 255, nn = rr >> 5, f = rr & 31;
    xTh[((size_t)(b * TB + t) * NB + n0 + nn) * FB + f] = f2b(xl[(nn * 32 + f) * 25 + t]);
  }
}

extern "C" void kernel_launch(void* const* d_in, const int* in_sizes, int n_in,
                              void* d_out, int out_size, void* d_ws, size_t ws_size,
                              hipStream_t stream){
  const float* x  = (const float*)d_in[0];
  const int*   ei = (const int*)d_in[1];
  const float* ew = (const float*)d_in[2];
  const float* Ve = (const float*)d_in[3];
  const float* be = (const float*)d_in[4];
  const float* Vs = (const float*)d_in[5];
  const float* bs = (const float*)d_in[6];
  const float* cW = (const float*)d_in[7];
  const float* cB = (const float*)d_in[8];
  const float* rW = (const float*)d_in[9];
  const float* rB = (const float*)d_in[10];
  float* out = (float*)d_out;

  char* W = (char*)d_ws;
  // region plan (bytes), aliased by lifetime; total ~92.5 MB
  unsigned short* sigh  = (unsigned short*)(W + 0);          // 16777216 B: sig(score_s) -> later Sh
  unsigned short* Sh    = sigh;                              // softmax out (after sigh dead)
  unsigned short* xTAh  = (unsigned short*)(W + 16777216);   // 12582912 B: xTA bf16 -> later T0h
  unsigned short* T0h   = xTAh;
  unsigned short* xTAhT = (unsigned short*)(W + 29360128);   // 12582912 B: xTA^T -> later T1h
  unsigned short* T1h   = xTAhT;
  unsigned short* xTh   = (unsigned short*)(W + 41943040);   // 12582912 B: x transposed bf16
  unsigned short* xSAh  = (unsigned short*)(W + 54525952);   // 12582912 B: xSA bf16 -> later T2h
  unsigned short* T2h   = xSAh;
  unsigned short* C2h   = (unsigned short*)(W + 67108864);   // 16777216 B logits -> Ct (25165824 B)
  unsigned short* Ct    = C2h;
  unsigned short* Vsh   = (unsigned short*)(W + 67108864 + 16777216); // 2097152 B (dead before Ct)
  unsigned short* Wh    = (unsigned short*)(W + 92274688);   // 16384 B
  float* bsum  = (float*)(W + 92291072);                     // 256 B
  float* score = (float*)(W + 92291328);                     // 18432 B
  float* Eatt  = (float*)(W + 92309760);                     // 18432 B
  float* normv = (float*)(W + 92328192);                     // 65536 B
  float* deg   = (float*)(W + 92393728);                     // 4096 B
  int*   cnt   = (int*)(W + 92397824);                       // 4096 B
  int*   ptr   = (int*)(W + 92401920);                       // 4352 B
  int*   fill  = (int*)(W + 92406272);                       // 4096 B
  int*   cidx  = (int*)(W + 92410368);                       // 65536 B

  hipMemsetAsync(score, 0, 18432, stream);
  hipMemsetAsync(deg, 0, 8192, stream);   // deg + cnt (contiguous)

  // constants / layout transforms
  k_wcat<<<1, 256, 0, stream>>>(cW, cB, rW, rB, Wh, bsum);
  k_vsh<<<1024, 256, 0, stream>>>(Vs, Vsh);
  k_xth<<<dim3(128, 8), 256, 0, stream>>>(x, xTh);

  // temporal attention
  k_score<<<dim3(64, 8), 256, 0, stream>>>(x, score);
  k_eatt<<<8, 64, 0, stream>>>(score, Ve, be, Eatt);
  k_xta<<<1024, 256, 0, stream>>>(x, Eatt, xTAh);
  k_tr<<<dim3(12, 16, 8), 256, 0, stream>>>(xTAh, xTAhT);

  // spatial attention: three bf16 MFMA GEMMs (sig symmetric -> all are A*B^T)
  k_mgemm<1><<<dim3(8, 8, 8), 256, 0, stream>>>(xTAh, xTAh, sigh, DB, DB, NB, DB,
                                                (long)NB*DB, (long)NB*DB, (long)NB*NB);
  k_mgemm<2><<<dim3(8, 8, 8), 256, 0, stream>>>(Vsh, sigh, C2h, NB, NB, NB, NB,
                                                0L, (long)NB*NB, (long)NB*NB);
  k_softmax_s<<<8192, 256, 0, stream>>>(C2h, bs, Sh);
  k_mgemm<2><<<dim3(6, 8, 8), 256, 0, stream>>>(Sh, xTAhT, xSAh, NB, NB, DB, NB,
                                                (long)NB*NB, (long)NB*DB, (long)NB*DB);

  // ChebConv: layout + CSR + 2 props (bf16 storage, f32 accumulate)
  k_t0h<<<dim3(128, 8), 256, 0, stream>>>(xSAh, T0h);
  k_edge_deg<<<64, 256, 0, stream>>>(ei, ew, deg, cnt);
  k_scan<<<1, 1024, 0, stream>>>(cnt, ptr, fill);
  k_edge_fill<<<64, 256, 0, stream>>>(ei, ew, deg, fill, cidx, normv);
  k_prop<<<dim3(128, 192), 256, 0, stream>>>(T0h, normv, cidx, ei, ptr, nullptr, 1.f, T1h);
  k_prop<<<dim3(128, 192), 256, 0, stream>>>(T1h, normv, cidx, ei, ptr, T0h, 2.f, T2h);

  // fused Cheb matmuls + residual + bias + relu (MFMA), then relayout to (b,n,g,t)
  k_fgemm<<<dim3(8, 192), 256, 0, stream>>>(T0h, T1h, T2h, xTh, Wh, bsum, Ct);
  k_outt<<<dim3(128, 8), 256, 0, stream>>>(Ct, out);
}

// Round 3
// 282.136 us; speedup vs baseline: 4.6704x; 2.1290x over previous
//
#include <hip/hip_runtime.h>
#include <math.h>

// Problem constants
#define NB 1024     // nodes
#define FB 32       // F_IN
#define TB 24       // T
#define GB 64       // F_OUT
#define BB 8        // batch
#define EB 16384    // edges
#define MB 32768    // N*F
#define DB 768      // F*T
#define BTB 192     // B*T
#define WSP 6144    // BT*F width of node-major T matrices

typedef __attribute__((ext_vector_type(8))) short sh8;     // 8 bf16 (4 VGPRs)
typedef __attribute__((ext_vector_type(4))) float f32x4;   // MFMA accumulator

__device__ __forceinline__ float wsum(float v){
  #pragma unroll
  for (int o = 32; o; o >>= 1) v += __shfl_down(v, o);
  return v;
}
__device__ __forceinline__ float wmax(float v){
  #pragma unroll
  for (int o = 32; o; o >>= 1) v = fmaxf(v, __shfl_down(v, o));
  return v;
}
__device__ __forceinline__ float sigm(float v){ return 1.f / (1.f + expf(-v)); }
__device__ __forceinline__ float b2f(unsigned short u){ unsigned int t = ((unsigned int)u) << 16; return __uint_as_float(t); }
__device__ __forceinline__ unsigned short f2b(float f){
  unsigned int u = __float_as_uint(f);
  u += 0x7fffu + ((u >> 16) & 1u);
  return (unsigned short)(u >> 16);
}
__device__ __forceinline__ void gload16(const void* g, void* l){
  typedef const __attribute__((address_space(1))) unsigned int* gp_t;
  typedef __attribute__((address_space(3))) unsigned int* lp_t;
  __builtin_amdgcn_global_load_lds((gp_t)g, (lp_t)l, 16, 0, 0);
}

// ---------------- temporal attention ----------------
__global__ __launch_bounds__(256) void k_score(const float* __restrict__ x,
                                               float* __restrict__ score){
  const int b = blockIdx.y, ch = blockIdx.x;   // 64 chunks of 512 rows
  __shared__ float xs[512 * 24];
  const float* src = x + (size_t)b * (MB * TB) + (size_t)ch * 512 * 24;
  #pragma unroll
  for (int p = 0; p < 12; ++p){
    int i = p * 256 + threadIdx.x;
    ((float4*)xs)[i] = ((const float4*)src)[i];
  }
  __syncthreads();
  if (threadIdx.x < 192){
    const int t = threadIdx.x >> 3, u0 = (threadIdx.x & 7) * 3;
    float a0 = 0.f, a1 = 0.f, a2 = 0.f;
    for (int m = 0; m < 512; ++m){
      const float xt = xs[m * 24 + t];
      a0 = fmaf(xt, xs[m * 24 + u0 + 0], a0);
      a1 = fmaf(xt, xs[m * 24 + u0 + 1], a1);
      a2 = fmaf(xt, xs[m * 24 + u0 + 2], a2);
    }
    float* sb = score + (size_t)b * 576 + t * 24 + u0;
    atomicAdd(sb + 0, a0); atomicAdd(sb + 1, a1); atomicAdd(sb + 2, a2);
  }
}

__global__ __launch_bounds__(64) void k_eatt(const float* __restrict__ score,
                                             const float* __restrict__ Ve,
                                             const float* __restrict__ be,
                                             float* __restrict__ Eatt){
  const int b = blockIdx.x;
  __shared__ float sg[576], Ar[576], Vel[576], bel[576];
  for (int i = threadIdx.x; i < 576; i += 64){
    sg[i] = sigm(score[(size_t)b * 576 + i]);
    Vel[i] = Ve[i]; bel[i] = be[i];
  }
  __syncthreads();
  for (int i = threadIdx.x; i < 576; i += 64){
    int t = i / 24, v = i % 24;
    float s = 0.f;
    #pragma unroll
    for (int u = 0; u < 24; ++u) s = fmaf(Vel[t*24+u], sg[u*24+v], s);
    Ar[i] = s + bel[i];
  }
  __syncthreads();
  if (threadIdx.x < 24){
    const int t = threadIdx.x;
    float mx = -1e30f;
    #pragma unroll
    for (int v = 0; v < 24; ++v) mx = fmaxf(mx, Ar[t*24+v]);
    float e[24]; float sum = 0.f;
    #pragma unroll
    for (int v = 0; v < 24; ++v){ e[v] = expf(Ar[t*24+v] - mx); sum += e[v]; }
    const float inv = 1.f / sum;
    #pragma unroll
    for (int v = 0; v < 24; ++v) Eatt[(size_t)b * 576 + t*24 + v] = e[v] * inv;
  }
}

__global__ __launch_bounds__(256) void k_xta(const float* __restrict__ x,
                                             const float* __restrict__ Eatt,
                                             unsigned short* __restrict__ xh){
  __shared__ float E[576];
  const int b = blockIdx.x >> 7;   // 128 blocks per batch
  for (int i = threadIdx.x; i < 576; i += 256) E[i] = Eatt[(size_t)b * 576 + i];
  __syncthreads();
  const size_t m = (size_t)blockIdx.x * 256 + threadIdx.x;
  const float* xr = x + m * TB;
  float in[TB], o[TB];
  #pragma unroll
  for (int q = 0; q < 6; ++q){
    float4 v = *(const float4*)(xr + q * 4);
    in[q*4+0] = v.x; in[q*4+1] = v.y; in[q*4+2] = v.z; in[q*4+3] = v.w;
  }
  #pragma unroll
  for (int v = 0; v < TB; ++v) o[v] = 0.f;
  #pragma unroll
  for (int u = 0; u < TB; ++u){
    const float xv = in[u];
    #pragma unroll
    for (int v = 0; v < TB; ++v) o[v] = fmaf(xv, E[u*24+v], o[v]);
  }
  unsigned int pk[12];
  #pragma unroll
  for (int q = 0; q < 12; ++q)
    pk[q] = (unsigned int)f2b(o[2*q]) | ((unsigned int)f2b(o[2*q+1]) << 16);
  uint4* op = (uint4*)(xh + m * TB);
  op[0] = make_uint4(pk[0], pk[1], pk[2], pk[3]);
  op[1] = make_uint4(pk[4], pk[5], pk[6], pk[7]);
  op[2] = make_uint4(pk[8], pk[9], pk[10], pk[11]);
}

// transpose per batch: (1024 x 768) -> (768 x 1024), bf16
__global__ __launch_bounds__(256) void k_tr(const unsigned short* __restrict__ in,
                                            unsigned short* __restrict__ out){
  const int dt = blockIdx.x, nt = blockIdx.y, b = blockIdx.z;
  __shared__ unsigned short ts[64 * 66];
  const unsigned short* ib = in + (size_t)b * (NB * DB) + (size_t)(nt * 64) * DB + dt * 64;
  #pragma unroll
  for (int p = 0; p < 8; ++p){
    int fl = p * 256 + threadIdx.x;
    int rr = fl >> 5, cc = (fl & 31) * 2;
    unsigned int v = *(const unsigned int*)(ib + (size_t)rr * DB + cc);
    ts[rr * 66 + cc] = (unsigned short)v;
    ts[rr * 66 + cc + 1] = (unsigned short)(v >> 16);
  }
  __syncthreads();
  unsigned short* ob = out + (size_t)b * (NB * DB) + (size_t)(dt * 64) * NB + nt * 64;
  #pragma unroll
  for (int p = 0; p < 16; ++p){
    int fl = p * 256 + threadIdx.x;
    int dd = fl >> 6, nn = fl & 63;
    ob[(size_t)dd * NB + nn] = ts[nn * 66 + dd];
  }
}

// ---------------- bf16 MFMA GEMM: C[i,j] = sum_k A[i,k]*B[j,k] ----------------
template<int EPI>
__global__ __launch_bounds__(256) void k_mgemm(const unsigned short* __restrict__ A,
                                               const unsigned short* __restrict__ B,
                                               unsigned short* __restrict__ C,
                                               int lda, int ldb, int ldc, int Kk,
                                               long sA, long sB, long sC){
  __shared__ unsigned short As[8192];
  __shared__ unsigned short Bs[8192];
  const int bz = blockIdx.z;
  A += (size_t)bz * sA; B += (size_t)bz * sB; C += (size_t)bz * sC;
  const int i0 = blockIdx.y * 128, j0 = blockIdx.x * 128;
  const int tid = threadIdx.x, wave = tid >> 6, lane = tid & 63;
  const int fr = lane & 15, fg = (lane >> 4) * 8, rowb = (lane >> 4) * 4;
  const int wr = (wave >> 1) * 64, wc = (wave & 1) * 64;
  const int srow = tid >> 3, sko = (tid & 7) * 8;
  f32x4 acc[4][4];
  #pragma unroll
  for (int m = 0; m < 4; ++m)
    #pragma unroll
    for (int n = 0; n < 4; ++n) acc[m][n] = 0.f;

  for (int k0 = 0; k0 < Kk; k0 += 64){
    #pragma unroll
    for (int it = 0; it < 4; ++it){
      const int r = it * 32 + srow;
      gload16(A + (size_t)(i0 + r) * lda + k0 + sko, &As[(it*4 + wave) * 512]);
      gload16(B + (size_t)(j0 + r) * ldb + k0 + sko, &Bs[(it*4 + wave) * 512]);
    }
    __syncthreads();
    #pragma unroll
    for (int kk = 0; kk < 2; ++kk){
      sh8 af[4], bfr[4];
      #pragma unroll
      for (int m = 0; m < 4; ++m)
        af[m] = *(const sh8*)&As[(wr + m*16 + fr) * 64 + kk*32 + fg];
      #pragma unroll
      for (int n = 0; n < 4; ++n)
        bfr[n] = *(const sh8*)&Bs[(wc + n*16 + fr) * 64 + kk*32 + fg];
      #pragma unroll
      for (int m = 0; m < 4; ++m)
        #pragma unroll
        for (int n = 0; n < 4; ++n)
          acc[m][n] = __builtin_amdgcn_mfma_f32_16x16x32_bf16(af[m], bfr[n], acc[m][n], 0, 0, 0);
    }
    __syncthreads();
  }
  #pragma unroll
  for (int m = 0; m < 4; ++m){
    const int row = i0 + wr + m*16 + rowb;
    #pragma unroll
    for (int n = 0; n < 4; ++n){
      const int colg = j0 + wc + n*16 + fr;
      #pragma unroll
      for (int r = 0; r < 4; ++r){
        float v = acc[m][n][r];
        if (EPI == 1) v = sigm(v);
        C[(size_t)(row + r) * ldc + colg] = f2b(v);
      }
    }
  }
}

// row softmax of (b2f(C2h) + bs) over last dim (1024) -> bf16 Sh
__global__ __launch_bounds__(256) void k_softmax_s(const unsigned short* __restrict__ C2h,
                                                   const float* __restrict__ bs,
                                                   unsigned short* __restrict__ Sh){
  const int blk = blockIdx.x;
  const int n = blk & 1023;
  const unsigned short* row = C2h + (size_t)blk * 1024;
  const float* bsr = bs + (size_t)n * 1024;
  const int tid = threadIdx.x;
  uint2 rv = ((const uint2*)row)[tid];
  float4 bb = ((const float4*)bsr)[tid];
  float v0 = b2f((unsigned short)rv.x)         + bb.x;
  float v1 = b2f((unsigned short)(rv.x >> 16)) + bb.y;
  float v2 = b2f((unsigned short)rv.y)         + bb.z;
  float v3 = b2f((unsigned short)(rv.y >> 16)) + bb.w;
  float mx = fmaxf(fmaxf(v0, v1), fmaxf(v2, v3));
  mx = wmax(mx);
  __shared__ float s4[4];
  __shared__ float s4b[4];
  if ((tid & 63) == 0) s4[tid >> 6] = mx;
  __syncthreads();
  mx = fmaxf(fmaxf(s4[0], s4[1]), fmaxf(s4[2], s4[3]));
  float e0 = expf(v0 - mx), e1 = expf(v1 - mx), e2 = expf(v2 - mx), e3 = expf(v3 - mx);
  float sum = wsum(e0 + e1 + e2 + e3);
  if ((tid & 63) == 0) s4b[tid >> 6] = sum;
  __syncthreads();
  sum = s4b[0] + s4b[1] + s4b[2] + s4b[3];
  const float inv = 1.f / sum;
  uint2 ov;
  ov.x = (unsigned int)f2b(e0 * inv) | ((unsigned int)f2b(e1 * inv) << 16);
  ov.y = (unsigned int)f2b(e2 * inv) | ((unsigned int)f2b(e3 * inv) << 16);
  ((uint2*)(Sh + (size_t)blk * 1024))[tid] = ov;
}

// T0n[(n*192 + b*24 + t)*32 + f] = xSA_h[b, n, f*24+t]   (node-major layout)
__global__ __launch_bounds__(256) void k_t0n(const unsigned short* __restrict__ xSAh,
                                             unsigned short* __restrict__ T0n){
  const int n0 = blockIdx.x * 8, b = blockIdx.y;
  __shared__ unsigned short s[8 * 32 * 25];
  const unsigned int* src = (const unsigned int*)(xSAh + ((size_t)b * NB + n0) * DB);
  #pragma unroll
  for (int p = 0; p < 12; ++p){
    int i = p * 256 + threadIdx.x;            // uint index over 3072
    unsigned int v = src[i];
    int d0 = (i * 2) % DB, nn = (i * 2) / DB;
    int f0 = d0 / 24, t0 = d0 % 24;
    int d1 = d0 + 1, f1 = d1 / 24, t1 = d1 % 24;
    s[(nn * 32 + f0) * 25 + t0] = (unsigned short)v;
    s[(nn * 32 + f1) * 25 + t1] = (unsigned short)(v >> 16);
  }
  __syncthreads();
  #pragma unroll
  for (int nn = 0; nn < 8; ++nn){
    unsigned short* dst = T0n + ((size_t)(n0 + nn) * BTB + b * TB) * FB;
    #pragma unroll
    for (int p = 0; p < 3; ++p){
      int i2 = p * 256 + threadIdx.x;         // 768 per node
      int t = i2 >> 5, f = i2 & 31;
      dst[t * FB + f] = s[(nn * 32 + f) * 25 + t];
    }
  }
}

// xTn[(n*192 + b*24 + t)*32 + f] = bf16(x[b,n,f,t])
__global__ __launch_bounds__(256) void k_xtn(const float* __restrict__ x,
                                             unsigned short* __restrict__ xTn){
  const int n0 = blockIdx.x * 8, b = blockIdx.y;
  __shared__ float xl[8 * 32 * 25];
  const float* src = x + ((size_t)b * NB + n0) * DB;
  #pragma unroll
  for (int p = 0; p < 24; ++p){
    int i = p * 256 + threadIdx.x;
    int n = i / 768, rem = i % 768, f = rem / 24, t = rem % 24;
    xl[(n * 32 + f) * 25 + t] = src[i];
  }
  __syncthreads();
  #pragma unroll
  for (int nn = 0; nn < 8; ++nn){
    unsigned short* dst = xTn + ((size_t)(n0 + nn) * BTB + b * TB) * FB;
    #pragma unroll
    for (int p = 0; p < 3; ++p){
      int i2 = p * 256 + threadIdx.x;
      int t = i2 >> 5, f = i2 & 31;
      dst[t * FB + f] = f2b(xl[(nn * 32 + f) * 25 + t]);
    }
  }
}

// ---------------- ChebConv graph machinery ----------------
__global__ __launch_bounds__(256) void k_edge_deg(const int* __restrict__ ei,
                                                  const float* __restrict__ ew,
                                                  float* __restrict__ deg,
                                                  int* __restrict__ cnt){
  int e = blockIdx.x * 256 + threadIdx.x;
  if (e >= EB) return;
  int r = ei[e], c = ei[EB + e];
  float w = (r == c) ? 0.f : ew[e];
  atomicAdd(&deg[r], w);
  atomicAdd(&cnt[c], 1);
}

__global__ __launch_bounds__(1024) void k_scan(const int* __restrict__ cnt,
                                               int* __restrict__ ptr,
                                               int* __restrict__ fill){
  __shared__ int sd[1024];
  const int i = threadIdx.x;
  int c = cnt[i];
  sd[i] = c;
  __syncthreads();
  int v = c;
  for (int s = 1; s < 1024; s <<= 1){
    int t = (i >= s) ? sd[i - s] : 0;
    __syncthreads();
    v += t; sd[i] = v;
    __syncthreads();
  }
  ptr[i + 1] = v;
  fill[i] = v - c;
  if (i == 0) ptr[0] = 0;
}

__global__ __launch_bounds__(256) void k_edge_fill(const int* __restrict__ ei,
                                                   const float* __restrict__ ew,
                                                   const float* __restrict__ deg,
                                                   int* __restrict__ fill,
                                                   int* __restrict__ cidx,
                                                   float* __restrict__ normv){
  int e = blockIdx.x * 256 + threadIdx.x;
  if (e >= EB) return;
  int r = ei[e], c = ei[EB + e];
  float w = (r == c) ? 0.f : ew[e];
  float dr = deg[r], dc = deg[c];
  float ir = dr > 0.f ? rsqrtf(dr) : 0.f;
  float ic = dc > 0.f ? rsqrtf(dc) : 0.f;
  normv[e] = -ir * w * ic;
  int pos = atomicAdd(&fill[c], 1);
  cidx[pos] = e;
}

// ---------------- streaming SpMM over node-major layout ----------------
// outz[c][v] = f2b( scale * sum_{e: col==c} norm[e] * b2f(z[row[e]][v]) - b2f(sub[c][v]) )
// v in [0, 6144); one block per column; edge metadata staged in LDS first.
#define ACC8(vv, base) { \
  acc[base+0] = fmaf(w, b2f((unsigned short)(vv).x), acc[base+0]); \
  acc[base+1] = fmaf(w, b2f((unsigned short)((vv).x >> 16)), acc[base+1]); \
  acc[base+2] = fmaf(w, b2f((unsigned short)(vv).y), acc[base+2]); \
  acc[base+3] = fmaf(w, b2f((unsigned short)((vv).y >> 16)), acc[base+3]); \
  acc[base+4] = fmaf(w, b2f((unsigned short)(vv).z), acc[base+4]); \
  acc[base+5] = fmaf(w, b2f((unsigned short)((vv).z >> 16)), acc[base+5]); \
  acc[base+6] = fmaf(w, b2f((unsigned short)(vv).w), acc[base+6]); \
  acc[base+7] = fmaf(w, b2f((unsigned short)((vv).w >> 16)), acc[base+7]); }

__global__ __launch_bounds__(256) void k_spmm(const unsigned short* __restrict__ z,
                                              const float* __restrict__ normv,
                                              const int* __restrict__ cidx,
                                              const int* __restrict__ ei,
                                              const int* __restrict__ ptr,
                                              const unsigned short* __restrict__ sub,
                                              float scale,
                                              unsigned short* __restrict__ outz){
  const int c = blockIdx.x;
  const int j0 = ptr[c], j1 = ptr[c + 1];
  __shared__ int rs[128];
  __shared__ float ws[128];
  const int off = threadIdx.x * 24;   // 24 elems / thread, 6144 total
  float acc[24];
  #pragma unroll
  for (int q = 0; q < 24; ++q) acc[q] = 0.f;
  for (int jb = j0; jb < j1; jb += 128){
    const int cnt = min(128, j1 - jb);
    __syncthreads();
    for (int j = threadIdx.x; j < cnt; j += 256){
      int e = cidx[jb + j];
      rs[j] = ei[e];
      ws[j] = normv[e];
    }
    __syncthreads();
    for (int j = 0; j < cnt; ++j){
      const uint4* zp = (const uint4*)(z + (size_t)rs[j] * WSP + off);
      const float w = ws[j];
      uint4 v0 = zp[0], v1 = zp[1], v2 = zp[2];
      ACC8(v0, 0) ACC8(v1, 8) ACC8(v2, 16)
    }
  }
  float sv[24];
  if (sub){
    const uint4* sp = (const uint4*)(sub + (size_t)c * WSP + off);
    uint4 s0 = sp[0], s1 = sp[1], s2 = sp[2];
    sv[0]=b2f((unsigned short)s0.x); sv[1]=b2f((unsigned short)(s0.x>>16));
    sv[2]=b2f((unsigned short)s0.y); sv[3]=b2f((unsigned short)(s0.y>>16));
    sv[4]=b2f((unsigned short)s0.z); sv[5]=b2f((unsigned short)(s0.z>>16));
    sv[6]=b2f((unsigned short)s0.w); sv[7]=b2f((unsigned short)(s0.w>>16));
    sv[8]=b2f((unsigned short)s1.x); sv[9]=b2f((unsigned short)(s1.x>>16));
    sv[10]=b2f((unsigned short)s1.y); sv[11]=b2f((unsigned short)(s1.y>>16));
    sv[12]=b2f((unsigned short)s1.z); sv[13]=b2f((unsigned short)(s1.z>>16));
    sv[14]=b2f((unsigned short)s1.w); sv[15]=b2f((unsigned short)(s1.w>>16));
    sv[16]=b2f((unsigned short)s2.x); sv[17]=b2f((unsigned short)(s2.x>>16));
    sv[18]=b2f((unsigned short)s2.y); sv[19]=b2f((unsigned short)(s2.y>>16));
    sv[20]=b2f((unsigned short)s2.z); sv[21]=b2f((unsigned short)(s2.z>>16));
    sv[22]=b2f((unsigned short)s2.w); sv[23]=b2f((unsigned short)(s2.w>>16));
  } else {
    #pragma unroll
    for (int q = 0; q < 24; ++q) sv[q] = 0.f;
  }
  unsigned int pk[12];
  #pragma unroll
  for (int q = 0; q < 12; ++q){
    float a = scale * acc[2*q]     - sv[2*q];
    float b = scale * acc[2*q + 1] - sv[2*q + 1];
    pk[q] = (unsigned int)f2b(a) | ((unsigned int)f2b(b) << 16);
  }
  uint4* op = (uint4*)(outz + (size_t)c * WSP + off);
  op[0] = make_uint4(pk[0], pk[1], pk[2], pk[3]);
  op[1] = make_uint4(pk[4], pk[5], pk[6], pk[7]);
  op[2] = make_uint4(pk[8], pk[9], pk[10], pk[11]);
}

// ---------------- fused final GEMM: Ct[m,g] = relu(A[m,:]@W[:,g] + bias) ----------------
// m = n*192 + b*24 + t; A row = [T0n | T1n | T2n | xTn] (K=128). Tile 128 m x 64 g.
__global__ __launch_bounds__(256) void k_fgemm(const unsigned short* __restrict__ T0n,
                                               const unsigned short* __restrict__ T1n,
                                               const unsigned short* __restrict__ T2n,
                                               const unsigned short* __restrict__ xTn,
                                               const unsigned short* __restrict__ Wh,
                                               const float* __restrict__ bsum,
                                               unsigned short* __restrict__ Ct){
  __shared__ unsigned short As[16384];
  __shared__ unsigned short Ws[8192];
  const int m0 = blockIdx.x * 128;
  const int tid = threadIdx.x, wave = tid >> 6, lane = tid & 63;
  const int fr = lane & 15, fg = (lane >> 4) * 8, rowb = (lane >> 4) * 4;
  const int wr = (wave >> 1) * 64, wc = (wave & 1) * 32;
  #pragma unroll
  for (int it = 0; it < 8; ++it){
    int flat = (it * 256 + tid) * 8;
    int row = flat >> 7, ko = flat & 127;
    int ss = ko >> 5, off = ko & 31;
    const unsigned short* bp = (ss == 0) ? T0n : (ss == 1) ? T1n : (ss == 2) ? T2n : xTn;
    gload16(bp + (size_t)(m0 + row) * FB + off, &As[(it*4 + wave) * 512]);
  }
  #pragma unroll
  for (int it = 0; it < 4; ++it)
    gload16(Wh + (size_t)(it * 256 + tid) * 8, &Ws[(it*4 + wave) * 512]);
  __syncthreads();
  f32x4 acc[4][2];
  #pragma unroll
  for (int m = 0; m < 4; ++m){ acc[m][0] = 0.f; acc[m][1] = 0.f; }
  #pragma unroll
  for (int kk = 0; kk < 4; ++kk){
    sh8 af[4], bf2[2];
    #pragma unroll
    for (int m = 0; m < 4; ++m)
      af[m] = *(const sh8*)&As[(wr + m*16 + fr) * 128 + kk*32 + fg];
    #pragma unroll
    for (int n = 0; n < 2; ++n)
      bf2[n] = *(const sh8*)&Ws[(wc + n*16 + fr) * 128 + kk*32 + fg];
    #pragma unroll
    for (int m = 0; m < 4; ++m)
      #pragma unroll
      for (int n = 0; n < 2; ++n)
        acc[m][n] = __builtin_amdgcn_mfma_f32_16x16x32_bf16(af[m], bf2[n], acc[m][n], 0, 0, 0);
  }
  #pragma unroll
  for (int n = 0; n < 2; ++n){
    const int g = wc + n*16 + fr;
    const float bv = bsum[g];
    #pragma unroll
    for (int m = 0; m < 4; ++m){
      const int row = m0 + wr + m*16 + rowb;
      #pragma unroll
      for (int r = 0; r < 4; ++r){
        float v = fmaxf(acc[m][n][r] + bv, 0.f);
        Ct[(size_t)(row + r) * GB + g] = f2b(v);
      }
    }
  }
}

// out[b,n,g,t] = f32(Ct[(n*192 + b*24 + t), g])
__global__ __launch_bounds__(256) void k_outt(const unsigned short* __restrict__ Ct,
                                              float* __restrict__ out){
  const int n0 = blockIdx.x * 8, b = blockIdx.y;
  __shared__ unsigned short ls[8 * 1536];
  #pragma unroll
  for (int nn = 0; nn < 8; ++nn){
    const unsigned int* src = (const unsigned int*)(Ct + ((size_t)(n0 + nn) * BTB + b * TB) * GB);
    unsigned int* dst = (unsigned int*)&ls[nn * 1536];
    dst[threadIdx.x] = src[threadIdx.x];
    dst[threadIdx.x + 256] = src[threadIdx.x + 256];
    dst[threadIdx.x + 512] = src[threadIdx.x + 512];
  }
  __syncthreads();
  #pragma unroll
  for (int pp = 0; pp < 2; ++pp){
    int p = pp * 256 + threadIdx.x;
    int nn = p >> 6, g = p & 63;
    float o[24];
    #pragma unroll
    for (int t = 0; t < 24; ++t) o[t] = b2f(ls[nn * 1536 + t * 64 + g]);
    float4* op = (float4*)(out + ((size_t)(b * NB + n0 + nn) * GB + g) * TB);
    #pragma unroll
    for (int q = 0; q < 6; ++q) op[q] = make_float4(o[q*4], o[q*4+1], o[q*4+2], o[q*4+3]);
  }
}

// ---------------- small converters ----------------
__global__ __launch_bounds__(256) void k_vsh(const float* __restrict__ Vs,
                                             unsigned short* __restrict__ Vsh){
  int i = (blockIdx.x * 256 + threadIdx.x) * 4;
  float4 v = *(const float4*)(Vs + i);
  unsigned short* o = Vsh + i;
  o[0] = f2b(v.x); o[1] = f2b(v.y); o[2] = f2b(v.z); o[3] = f2b(v.w);
}

__global__ __launch_bounds__(256) void k_wcat(const float* __restrict__ cW,
                                              const float* __restrict__ cB,
                                              const float* __restrict__ rW,
                                              const float* __restrict__ rB,
                                              unsigned short* __restrict__ Wh,
                                              float* __restrict__ bsum){
  for (int i = threadIdx.x; i < 8192; i += 256){
    int g = i >> 7, k = i & 127;
    int s = k >> 5, f = k & 31;
    float v = (s < 3) ? cW[(s * 32 + f) * 64 + g] : rW[g * 32 + f];
    Wh[i] = f2b(v);
  }
  if (threadIdx.x < 64) bsum[threadIdx.x] = cB[threadIdx.x] + rB[threadIdx.x];
}

extern "C" void kernel_launch(void* const* d_in, const int* in_sizes, int n_in,
                              void* d_out, int out_size, void* d_ws, size_t ws_size,
                              hipStream_t stream){
  const float* x  = (const float*)d_in[0];
  const int*   ei = (const int*)d_in[1];
  const float* ew = (const float*)d_in[2];
  const float* Ve = (const float*)d_in[3];
  const float* be = (const float*)d_in[4];
  const float* Vs = (const float*)d_in[5];
  const float* bs = (const float*)d_in[6];
  const float* cW = (const float*)d_in[7];
  const float* cB = (const float*)d_in[8];
  const float* rW = (const float*)d_in[9];
  const float* rB = (const float*)d_in[10];
  float* out = (float*)d_out;

  char* W = (char*)d_ws;
  unsigned short* sigh  = (unsigned short*)(W + 0);          // 16 MB: sig(score_s) -> later Sh
  unsigned short* Sh    = sigh;
  unsigned short* xTAh  = (unsigned short*)(W + 16777216);   // 12 MB: xTA bf16 -> later T0n
  unsigned short* T0n   = xTAh;
  unsigned short* xTAhT = (unsigned short*)(W + 29360128);   // 12 MB: xTA^T -> later T1n
  unsigned short* T1n   = xTAhT;
  unsigned short* xTn   = (unsigned short*)(W + 41943040);   // 12 MB: x node-major bf16
  unsigned short* xSAh  = (unsigned short*)(W + 54525952);   // 12 MB: xSA bf16 -> later T2n
  unsigned short* T2n   = xSAh;
  unsigned short* C2h   = (unsigned short*)(W + 67108864);   // 16 MB logits -> Ct (24 MB)
  unsigned short* Ct    = C2h;
  unsigned short* Vsh   = (unsigned short*)(W + 83886080);   // 2 MB (dead before Ct grows)
  unsigned short* Wh    = (unsigned short*)(W + 92274688);   // 16 KB
  float* bsum  = (float*)(W + 92291072);
  float* score = (float*)(W + 92291328);
  float* Eatt  = (float*)(W + 92309760);
  float* normv = (float*)(W + 92328192);
  float* deg   = (float*)(W + 92393728);
  int*   cnt   = (int*)(W + 92397824);
  int*   ptr   = (int*)(W + 92401920);
  int*   fill  = (int*)(W + 92406272);
  int*   cidx  = (int*)(W + 92410368);

  hipMemsetAsync(score, 0, 18432, stream);
  hipMemsetAsync(deg, 0, 8192, stream);   // deg + cnt (contiguous)

  // constants / layout transforms
  k_wcat<<<1, 256, 0, stream>>>(cW, cB, rW, rB, Wh, bsum);
  k_vsh<<<1024, 256, 0, stream>>>(Vs, Vsh);
  k_xtn<<<dim3(128, 8), 256, 0, stream>>>(x, xTn);

  // temporal attention
  k_score<<<dim3(64, 8), 256, 0, stream>>>(x, score);
  k_eatt<<<8, 64, 0, stream>>>(score, Ve, be, Eatt);
  k_xta<<<1024, 256, 0, stream>>>(x, Eatt, xTAh);
  k_tr<<<dim3(12, 16, 8), 256, 0, stream>>>(xTAh, xTAhT);

  // spatial attention: three bf16 MFMA GEMMs
  k_mgemm<1><<<dim3(8, 8, 8), 256, 0, stream>>>(xTAh, xTAh, sigh, DB, DB, NB, DB,
                                                (long)NB*DB, (long)NB*DB, (long)NB*NB);
  k_mgemm<2><<<dim3(8, 8, 8), 256, 0, stream>>>(Vsh, sigh, C2h, NB, NB, NB, NB,
                                                0L, (long)NB*NB, (long)NB*NB);
  k_softmax_s<<<8192, 256, 0, stream>>>(C2h, bs, Sh);
  k_mgemm<2><<<dim3(6, 8, 8), 256, 0, stream>>>(Sh, xTAhT, xSAh, NB, NB, DB, NB,
                                                (long)NB*NB, (long)NB*DB, (long)NB*DB);

  // ChebConv: node-major layout + CSR + 2 streaming SpMMs
  k_t0n<<<dim3(128, 8), 256, 0, stream>>>(xSAh, T0n);
  k_edge_deg<<<64, 256, 0, stream>>>(ei, ew, deg, cnt);
  k_scan<<<1, 1024, 0, stream>>>(cnt, ptr, fill);
  k_edge_fill<<<64, 256, 0, stream>>>(ei, ew, deg, fill, cidx, normv);
  k_spmm<<<1024, 256, 0, stream>>>(T0n, normv, cidx, ei, ptr, nullptr, 1.f, T1n);
  k_spmm<<<1024, 256, 0, stream>>>(T1n, normv, cidx, ei, ptr, T0n, 2.f, T2n);

  // fused Cheb matmuls + residual + bias + relu (MFMA), then relayout to (b,n,g,t)
  k_fgemm<<<1536, 256, 0, stream>>>(T0n, T1n, T2n, xTn, Wh, bsum, Ct);
  k_outt<<<dim3(128, 8), 256, 0, stream>>>(Ct, out);
}